// Round 6
// baseline (215.028 us; speedup 1.0000x reference)
//
#include <hip/hip_runtime.h>
#include <hip/hip_cooperative_groups.h>

namespace cg = cooperative_groups;

// logits: [E=4, B=8192, C=1000] f32 (131 MB, memory-bound), target: [B] i32,
// out: [E] f32.  loss[e] = (1/(B*C)) * sum_c |colsum(logits[e])[c] - hist(target)[c]|
constexpr int E_  = 4;
constexpr int B_  = 8192;
constexpr int C_  = 1000;
constexpr int CQ_ = C_ / 4;             // 250 float4 column-quads
constexpr int NB_ = 64;                 // batch rows per block
constexpr int NBLK_  = E_ * B_ / NB_;   // 512 blocks
constexpr int GRP_   = 16;              // partial rows per phase-2 reducer
constexpr int NGRP_  = NBLK_ / GRP_;    // 32 level-2 rows
constexpr int GPE_   = NGRP_ / E_;      // 8 level-2 rows per exit

// ws layout: partial[NBLK_*C_] f32 | level2[NGRP_*C_] f32 | counts[C_] f32
constexpr size_t PARTIAL_BYTES = (size_t)NBLK_ * C_ * sizeof(float); // 2,048,000
constexpr size_t LEVEL2_OFF    = PARTIAL_BYTES;
constexpr size_t LEVEL2_BYTES  = (size_t)NGRP_ * C_ * sizeof(float); // 128,000
constexpr size_t COUNTS_OFF    = LEVEL2_OFF + LEVEL2_BYTES;          // 16B-aligned
constexpr size_t COOP_BYTES    = COUNTS_OFF + C_ * sizeof(float);

// =============== cooperative single-dispatch kernel (no tickets) =============
// grid.sync() is the driver-blessed grid barrier (harness-supported). No block
// returns early; every thread executes both syncs. No custom fence protocol.
__global__ __launch_bounds__(256, 2) void mdca_coop(
        const float* __restrict__ logits, const int* __restrict__ target,
        float* __restrict__ partial, float* __restrict__ level2,
        float* __restrict__ counts, float* __restrict__ out) {
    cg::grid_group grid = cg::this_grid();
    const int b = blockIdx.x;
    const int t = threadIdx.x;

    // ---- phase 1: column-sum 64 rows, store partial row (non-atomic) ----
    if (t < CQ_) {
        const float4* base = reinterpret_cast<const float4*>(logits)
                           + (size_t)b * NB_ * CQ_ + t;
        float4 acc = make_float4(0.f, 0.f, 0.f, 0.f);
        #pragma unroll 8
        for (int r = 0; r < NB_; ++r) {
            float4 v = base[(size_t)r * CQ_];
            acc.x += v.x; acc.y += v.y; acc.z += v.z; acc.w += v.w;
        }
        reinterpret_cast<float4*>(partial)[(size_t)b * CQ_ + t] = acc;
    }
    __threadfence();
    grid.sync();

    // ---- phase 2: 32 reducer blocks + 1 histogram block (concurrent) ----
    if (b < NGRP_) {
        if (t < CQ_) {
            const float4* p = reinterpret_cast<const float4*>(partial)
                            + (size_t)b * GRP_ * CQ_ + t;
            float4 acc = make_float4(0.f, 0.f, 0.f, 0.f);
            #pragma unroll
            for (int k = 0; k < GRP_; ++k) {
                float4 v = p[(size_t)k * CQ_];
                acc.x += v.x; acc.y += v.y; acc.z += v.z; acc.w += v.w;
            }
            reinterpret_cast<float4*>(level2)[(size_t)b * CQ_ + t] = acc;
        }
    } else if (b == NGRP_) {
        __shared__ int lh[C_];
        for (int i = t; i < C_; i += 256) lh[i] = 0;
        __syncthreads();
        for (int i = t; i < B_; i += 256) atomicAdd(&lh[target[i]], 1);
        __syncthreads();
        for (int i = t; i < C_; i += 256) counts[i] = (float)lh[i];
    }
    __threadfence();
    grid.sync();

    // ---- phase 3: blocks 0..3 produce out[e] ----
    if (b < E_) {
        float s = 0.f;
        if (t < CQ_) {
            const float4* p = reinterpret_cast<const float4*>(level2)
                            + (size_t)b * GPE_ * CQ_ + t;
            float4 acc = make_float4(0.f, 0.f, 0.f, 0.f);
            #pragma unroll
            for (int k = 0; k < GPE_; ++k) {
                float4 v = p[(size_t)k * CQ_];
                acc.x += v.x; acc.y += v.y; acc.z += v.z; acc.w += v.w;
            }
            float4 cn = reinterpret_cast<const float4*>(counts)[t];
            s = fabsf(acc.x - cn.x) + fabsf(acc.y - cn.y)
              + fabsf(acc.z - cn.z) + fabsf(acc.w - cn.w);
        }
        #pragma unroll
        for (int off = 32; off > 0; off >>= 1) s += __shfl_down(s, off);
        __shared__ float red[4];
        if ((t & 63) == 0) red[t >> 6] = s;
        __syncthreads();
        if (t == 0) out[b] = (red[0] + red[1] + red[2] + red[3])
                             / ((float)B_ * (float)C_);
    }
}

// ============ fallback: proven R2 two-dispatch path (ws >= 2 MB) =============
__global__ __launch_bounds__(256) void colsum_partial(
        const float* __restrict__ logits, float* __restrict__ partial) {
    const int b = blockIdx.x, t = threadIdx.x;
    if (t >= CQ_) return;
    const float4* base = reinterpret_cast<const float4*>(logits)
                       + (size_t)b * NB_ * CQ_ + t;
    float4 acc = make_float4(0.f, 0.f, 0.f, 0.f);
    #pragma unroll 8
    for (int r = 0; r < NB_; ++r) {
        float4 v = base[(size_t)r * CQ_];
        acc.x += v.x; acc.y += v.y; acc.z += v.z; acc.w += v.w;
    }
    reinterpret_cast<float4*>(partial)[(size_t)b * CQ_ + t] = acc;
}

__global__ __launch_bounds__(1024) void finalize_partial(
        const float* __restrict__ partial, const int* __restrict__ target,
        float* __restrict__ out) {
    const int e = blockIdx.x, t = threadIdx.x;
    __shared__ int lh[C_];
    for (int i = t; i < C_; i += 1024) lh[i] = 0;
    __syncthreads();
    for (int i = t; i < B_; i += 1024) atomicAdd(&lh[target[i]], 1);
    __syncthreads();
    float s = 0.f;
    if (t < C_) {
        float sum = 0.f;
        const float* p = partial + (size_t)e * (B_ / NB_) * C_ + t;
        #pragma unroll 8
        for (int k = 0; k < B_ / NB_; ++k) sum += p[(size_t)k * C_];
        s = fabsf(sum - (float)lh[t]);
    }
    #pragma unroll
    for (int off = 32; off > 0; off >>= 1) s += __shfl_down(s, off);
    __shared__ float red[16];
    if ((t & 63) == 0) red[t >> 6] = s;
    __syncthreads();
    if (t == 0) {
        float tot = 0.f;
        #pragma unroll
        for (int w = 0; w < 16; ++w) tot += red[w];
        out[e] = tot / ((float)B_ * (float)C_);
    }
}

extern "C" void kernel_launch(void* const* d_in, const int* in_sizes, int n_in,
                              void* d_out, int out_size, void* d_ws, size_t ws_size,
                              hipStream_t stream) {
    const float* logits = (const float*)d_in[0];
    const int*   target = (const int*)d_in[1];
    float* out = (float*)d_out;
    float* part = (float*)d_ws;

    // Host-side capability gates (queries only — capture-safe, deterministic).
    bool coop_ok = (ws_size >= COOP_BYTES);
    if (coop_ok) {
        int dev = 0;
        (void)hipGetDevice(&dev);
        int has_coop = 0;
        if (hipDeviceGetAttribute(&has_coop, hipDeviceAttributeCooperativeLaunch,
                                  dev) != hipSuccess || !has_coop)
            coop_ok = false;
        if (coop_ok) {
            int blocks_per_cu = 0, num_cu = 0;
            if (hipOccupancyMaxActiveBlocksPerMultiprocessor(
                    &blocks_per_cu, mdca_coop, 256, 0) != hipSuccess ||
                hipDeviceGetAttribute(&num_cu,
                    hipDeviceAttributeMultiprocessorCount, dev) != hipSuccess ||
                blocks_per_cu * num_cu < NBLK_)
                coop_ok = false;
        }
    }

    if (coop_ok) {
        float* lvl2 = (float*)((char*)d_ws + LEVEL2_OFF);
        float* cnts = (float*)((char*)d_ws + COUNTS_OFF);
        void* args[] = {(void*)&logits, (void*)&target, (void*)&part,
                        (void*)&lvl2,   (void*)&cnts,   (void*)&out};
        hipError_t err = hipLaunchCooperativeKernel(
            (const void*)mdca_coop, dim3(NBLK_), dim3(256), args, 0, stream);
        if (err == hipSuccess) return;
        // fall through to the two-dispatch path on any launch failure
    }

    hipLaunchKernelGGL(colsum_partial, dim3(NBLK_), dim3(256), 0, stream,
                       logits, part);
    hipLaunchKernelGGL(finalize_partial, dim3(E_), dim3(1024), 0, stream,
                       part, target, out);
}

// Round 7
// 40.561 us; speedup vs baseline: 5.3013x; 5.3013x over previous
//
#include <hip/hip_runtime.h>

// logits: [E=4, B=8192, C=1000] f32 (131 MB, memory-bound), target: [B] i32,
// out: [E] f32.  loss[e] = (1/(B*C)) * sum_c |colsum(logits[e])[c] - hist(target)[c]|
//
// R6 lessons: cooperative grid.sync costs ~100us/sync on MI355X (measured
// 215-245us total) -> stay with the two-dispatch decoupled structure.
// Replays serve ~half the logits from L3 (FETCH 65MB of 131MB) -> colsum is
// latency-sensitive, so run 4 blocks/CU (16 waves/CU), not 2.
constexpr int E_  = 4;
constexpr int B_  = 8192;
constexpr int C_  = 1000;
constexpr int CQ_ = C_ / 4;             // 250 float4 column-quads
constexpr int NB_ = 32;                 // batch rows per colsum block
constexpr int NBLK_   = E_ * B_ / NB_;  // 1024 blocks = 4/CU = 16 waves/CU
constexpr int NCHUNK_ = B_ / NB_;       // 256 partial rows per exit

// ws: partial[NBLK_][C_] f32 (4,096,000 B)
__global__ __launch_bounds__(256) void colsum_partial(
        const float* __restrict__ logits, float* __restrict__ partial) {
    const int b = blockIdx.x, t = threadIdx.x;
    if (t >= CQ_) return;
    const float4* base = reinterpret_cast<const float4*>(logits)
                       + (size_t)b * NB_ * CQ_ + t;
    float4 acc = make_float4(0.f, 0.f, 0.f, 0.f);
    #pragma unroll 16
    for (int r = 0; r < NB_; ++r) {       // 16 loads in flight per wave
        float4 v = base[(size_t)r * CQ_];
        acc.x += v.x; acc.y += v.y; acc.z += v.z; acc.w += v.w;
    }
    reinterpret_cast<float4*>(partial)[(size_t)b * CQ_ + t] = acc;
}

// 4 blocks (one per exit) x 1024 threads (16 waves). Each block: LDS histogram
// of the 8192 targets (redundant, ~32KB), then reduce 256 partial rows per
// column (coalesced, ~1MB from L2/L3), |sum-count|, block-reduce, write out[e].
__global__ __launch_bounds__(1024) void finalize_partial(
        const float* __restrict__ partial, const int* __restrict__ target,
        float* __restrict__ out) {
    const int e = blockIdx.x, t = threadIdx.x;
    __shared__ int lh[C_];
    for (int i = t; i < C_; i += 1024) lh[i] = 0;
    __syncthreads();
    for (int i = t; i < B_; i += 1024) atomicAdd(&lh[target[i]], 1);
    __syncthreads();
    float s = 0.f;
    if (t < C_) {
        float sum = 0.f;
        const float* p = partial + (size_t)e * NCHUNK_ * C_ + t;
        #pragma unroll 8
        for (int k = 0; k < NCHUNK_; ++k) sum += p[(size_t)k * C_];
        s = fabsf(sum - (float)lh[t]);
    }
    #pragma unroll
    for (int off = 32; off > 0; off >>= 1) s += __shfl_down(s, off);
    __shared__ float red[16];
    if ((t & 63) == 0) red[t >> 6] = s;
    __syncthreads();
    if (t == 0) {
        float tot = 0.f;
        #pragma unroll
        for (int w = 0; w < 16; ++w) tot += red[w];
        out[e] = tot / ((float)B_ * (float)C_);
    }
}

extern "C" void kernel_launch(void* const* d_in, const int* in_sizes, int n_in,
                              void* d_out, int out_size, void* d_ws, size_t ws_size,
                              hipStream_t stream) {
    const float* logits = (const float*)d_in[0];
    const int*   target = (const int*)d_in[1];
    float* out  = (float*)d_out;
    float* part = (float*)d_ws;   // ws is ~512 MB (measured poison fill); 4 MB used

    hipLaunchKernelGGL(colsum_partial, dim3(NBLK_), dim3(256), 0, stream,
                       logits, part);
    hipLaunchKernelGGL(finalize_partial, dim3(E_), dim3(1024), 0, stream,
                       part, target, out);
}

// Round 10
// 36.937 us; speedup vs baseline: 5.8214x; 1.0981x over previous
//
#include <hip/hip_runtime.h>

// logits: [E=4, B=8192, C=1000] f32 (131 MB, memory-bound), target: [B] i32,
// out: [E] f32.  loss[e] = (1/(B*C)) * sum_c |colsum(logits[e])[c] - hist(target)[c]|
//
// Hard-won structure decisions (measured):
//  - coop grid.sync: ~100us/sync on MI355X (R6: 215-245us total) -> never.
//  - ticket/fence single-dispatch handoff: nondeterministic on HW (R8 tripwire;
//    cross-XCD stale reads despite threadfence+agent atomics) -> never.
//  - two plain dispatches (R2): 33.7us, deterministic. The dispatch boundary is
//    the only cheap correct global barrier -> optimize inside that structure.
//  - NB=32 (R7, 40.6us): doubling partial rows doubles the tail. Keep NB=64.
constexpr int E_  = 4;
constexpr int B_  = 8192;
constexpr int C_  = 1000;
constexpr int CQ_ = C_ / 4;             // 250 float4 column-quads
constexpr int NB_ = 64;                 // batch rows per colsum block
constexpr int NBLK_   = E_ * B_ / NB_;  // 512 blocks (2/CU, 8 waves/CU)
constexpr int NCHUNK_ = B_ / NB_;       // 128 partial rows per exit
constexpr int RG_     = 4;              // row-groups in finalize
constexpr int RPG_    = NCHUNK_ / RG_;  // 32 rows per row-group

// ws: partial[NBLK_][C_] f32 | counts[C_] f32
constexpr size_t PARTIAL_BYTES = (size_t)NBLK_ * C_ * sizeof(float); // 2,048,000
constexpr size_t COUNTS_OFF    = PARTIAL_BYTES;                      // 16B-aligned

// ---- dispatch 1: stream logits -> 512 partial rows; block 0 also histograms
// target into ws counts (overlapped with the stream; visibility to dispatch 2
// is provided by the dispatch boundary, no cross-block races: only block 0
// writes counts, nobody reads it until the next dispatch).
__global__ __launch_bounds__(256) void colsum_hist(
        const float* __restrict__ logits, const int* __restrict__ target,
        float* __restrict__ partial, float* __restrict__ counts) {
    const int b = blockIdx.x, t = threadIdx.x;

    if (t < CQ_) {
        const float4* base = reinterpret_cast<const float4*>(logits)
                           + (size_t)b * NB_ * CQ_ + t;
        float4 acc = make_float4(0.f, 0.f, 0.f, 0.f);
        #pragma unroll 8
        for (int r = 0; r < NB_; ++r) {
            float4 v = base[(size_t)r * CQ_];
            acc.x += v.x; acc.y += v.y; acc.z += v.z; acc.w += v.w;
        }
        reinterpret_cast<float4*>(partial)[(size_t)b * CQ_ + t] = acc;
    }

    if (b == 0) {   // histogram, hidden under the other 511 blocks' streaming
        __shared__ int lh[C_];
        for (int i = t; i < C_; i += 256) lh[i] = 0;
        __syncthreads();
        for (int i = t; i < B_; i += 256) atomicAdd(&lh[target[i]], 1);
        __syncthreads();
        for (int i = t; i < C_; i += 256) counts[i] = (float)lh[i];
    }
}

// ---- dispatch 2: 4 blocks (one per exit) x 1024. Threads (quad=t%250,
// rg=t/250) sum 32 rows each with float4 loads -> LDS -> combine 4 row-groups,
// |sum - counts|, block-reduce, write out[e]. Reads 512KB+1KB per block.
__global__ __launch_bounds__(1024) void finalize_partial(
        const float* __restrict__ partial, const float* __restrict__ counts,
        float* __restrict__ out) {
    const int e = blockIdx.x, t = threadIdx.x;
    const int q  = t % CQ_;
    const int rg = t / CQ_;

    __shared__ float4 l2[RG_][CQ_];
    if (t < RG_ * CQ_) {
        const float4* p = reinterpret_cast<const float4*>(partial)
                        + (size_t)(e * NCHUNK_ + rg * RPG_) * CQ_ + q;
        float4 a = make_float4(0.f, 0.f, 0.f, 0.f);
        #pragma unroll 8
        for (int k = 0; k < RPG_; ++k) {
            float4 v = p[(size_t)k * CQ_];
            a.x += v.x; a.y += v.y; a.z += v.z; a.w += v.w;
        }
        l2[rg][q] = a;
    }
    __syncthreads();

    float s = 0.f;
    if (t < CQ_) {
        float4 a = l2[0][t], b2 = l2[1][t], c = l2[2][t], d = l2[3][t];
        float4 cn = reinterpret_cast<const float4*>(counts)[t];
        s = fabsf(a.x + b2.x + c.x + d.x - cn.x)
          + fabsf(a.y + b2.y + c.y + d.y - cn.y)
          + fabsf(a.z + b2.z + c.z + d.z - cn.z)
          + fabsf(a.w + b2.w + c.w + d.w - cn.w);
    }
    #pragma unroll
    for (int off = 32; off > 0; off >>= 1) s += __shfl_down(s, off);
    __shared__ float red[16];
    if ((t & 63) == 0) red[t >> 6] = s;
    __syncthreads();
    if (t == 0) {
        float tot = 0.f;
        #pragma unroll
        for (int w = 0; w < 16; ++w) tot += red[w];
        out[e] = tot / ((float)B_ * (float)C_);
    }
}

extern "C" void kernel_launch(void* const* d_in, const int* in_sizes, int n_in,
                              void* d_out, int out_size, void* d_ws, size_t ws_size,
                              hipStream_t stream) {
    const float* logits = (const float*)d_in[0];
    const int*   target = (const int*)d_in[1];
    float* out  = (float*)d_out;
    float* part = (float*)d_ws;
    float* cnts = (float*)((char*)d_ws + COUNTS_OFF);

    hipLaunchKernelGGL(colsum_hist, dim3(NBLK_), dim3(256), 0, stream,
                       logits, target, part, cnts);
    hipLaunchKernelGGL(finalize_partial, dim3(E_), dim3(1024), 0, stream,
                       part, cnts, out);
}

// Round 11
// 35.595 us; speedup vs baseline: 6.0410x; 1.0377x over previous
//
#include <hip/hip_runtime.h>

// logits: [E=4, B=8192, C=1000] f32 (131 MB, memory-bound), target: [B] i32,
// out: [E] f32.  loss[e] = (1/(B*C)) * sum_c |colsum(logits[e])[c] - hist(target)[c]|
//
// Measured structure decisions:
//  - coop grid.sync: ~100us/sync (R6: 215us total) -> never.
//  - ticket/fence single-dispatch handoff: nondeterministic (R8 tripwire) -> never.
//  - hist inside colsum block 0: serializes on dispatch-1 critical path
//    (R10: 36.9 vs R2 33.7) -> hist gets its own extra block (concurrent).
//  - NB=32 (R7, 40.6us): doubling partials doubles the tail. Keep NB=64.
//  - 4-block finalize pulls 512KB/CU through L3 (~6-10us tail) -> column-sliced
//    250-block reduce + tiny final dispatch.
constexpr int E_  = 4;
constexpr int B_  = 8192;
constexpr int C_  = 1000;
constexpr int CQ_ = C_ / 4;             // 250 float4 column-quads
constexpr int NB_ = 64;                 // batch rows per colsum block
constexpr int NBLK_   = E_ * B_ / NB_;  // 512 colsum blocks
constexpr int NCHUNK_ = B_ / NB_;       // 128 partial rows per exit

// ws: partial[NBLK_][C_] f32 | counts[C_] f32 | colabs[E_][C_] f32
constexpr size_t PARTIAL_BYTES = (size_t)NBLK_ * C_ * sizeof(float); // 2,048,000
constexpr size_t COUNTS_OFF    = PARTIAL_BYTES;
constexpr size_t COLABS_OFF    = COUNTS_OFF + C_ * sizeof(float);

// ---- dispatch 1 (513 blocks): 512 colsum blocks + 1 histogram block --------
__global__ __launch_bounds__(256) void colsum_hist(
        const float* __restrict__ logits, const int* __restrict__ target,
        float* __restrict__ partial, float* __restrict__ counts) {
    const int b = blockIdx.x, t = threadIdx.x;

    if (b < NBLK_) {
        if (t >= CQ_) return;
        const float4* base = reinterpret_cast<const float4*>(logits)
                           + (size_t)b * NB_ * CQ_ + t;
        float4 acc = make_float4(0.f, 0.f, 0.f, 0.f);
        #pragma unroll 8
        for (int r = 0; r < NB_; ++r) {
            float4 v = base[(size_t)r * CQ_];
            acc.x += v.x; acc.y += v.y; acc.z += v.z; acc.w += v.w;
        }
        reinterpret_cast<float4*>(partial)[(size_t)b * CQ_ + t] = acc;
    } else {  // b == NBLK_: histogram, concurrent with the stream
        __shared__ int lh[C_];
        for (int i = t; i < C_; i += 256) lh[i] = 0;
        __syncthreads();
        for (int i = t; i < B_; i += 256) atomicAdd(&lh[target[i]], 1);
        __syncthreads();
        for (int i = t; i < C_; i += 256) counts[i] = (float)lh[i];
    }
}

// ---- dispatch 2 (250 blocks): block j owns col-quad j; reduce 512 rows ------
// Thread t sums rows t (exit t/128) and t+256 (exit 2 + t/128); LDS tree per
// 128-thread group gives the 4 per-exit column sums; write |sum - count|.
__global__ __launch_bounds__(256) void colreduce(
        const float* __restrict__ partial, const float* __restrict__ counts,
        float* __restrict__ colabs) {
    const int j = blockIdx.x, t = threadIdx.x;
    const float4* p = reinterpret_cast<const float4*>(partial) + j;

    float4 a = p[(size_t)t * CQ_];            // row t      (exit t/128)
    float4 b = p[(size_t)(t + 256) * CQ_];    // row t+256  (exit 2 + t/128)

    __shared__ float4 bufA[256], bufB[256];
    bufA[t] = a; bufB[t] = b;
    __syncthreads();
    // tree-reduce within each 128-thread half (rows of one exit stay together)
    const int half = t & 128;        // 0 or 128
    const int lane = t & 127;
    #pragma unroll
    for (int off = 64; off > 0; off >>= 1) {
        if (lane < off) {
            float4 xa = bufA[half + lane + off], xb = bufB[half + lane + off];
            float4 ya = bufA[half + lane],       yb = bufB[half + lane];
            ya.x += xa.x; ya.y += xa.y; ya.z += xa.z; ya.w += xa.w;
            yb.x += xb.x; yb.y += xb.y; yb.z += xb.z; yb.w += xb.w;
            bufA[half + lane] = ya; bufB[half + lane] = yb;
        }
        __syncthreads();
    }
    if (lane == 0) {
        const int eA = half >> 7;            // 0 or 1
        const int eB = 2 + (half >> 7);      // 2 or 3
        float4 sA = bufA[half], sB = bufB[half];
        float4 cn = reinterpret_cast<const float4*>(counts)[j];
        float4* oA = reinterpret_cast<float4*>(colabs + (size_t)eA * C_) + j;
        float4* oB = reinterpret_cast<float4*>(colabs + (size_t)eB * C_) + j;
        *oA = make_float4(fabsf(sA.x - cn.x), fabsf(sA.y - cn.y),
                          fabsf(sA.z - cn.z), fabsf(sA.w - cn.w));
        *oB = make_float4(fabsf(sB.x - cn.x), fabsf(sB.y - cn.y),
                          fabsf(sB.z - cn.z), fabsf(sB.w - cn.w));
    }
}

// ---- dispatch 3 (1 block): reduce colabs[E][C] (16 KB) -> out[E] ------------
__global__ __launch_bounds__(1024) void final_out(
        const float* __restrict__ colabs, float* __restrict__ out) {
    const int t = threadIdx.x;
    float se[E_] = {0.f, 0.f, 0.f, 0.f};
    if (t < C_) {
        #pragma unroll
        for (int e = 0; e < E_; ++e) se[e] = colabs[(size_t)e * C_ + t];
    }
    __shared__ float red[E_][16];
    #pragma unroll
    for (int e = 0; e < E_; ++e) {
        float s = se[e];
        #pragma unroll
        for (int off = 32; off > 0; off >>= 1) s += __shfl_down(s, off);
        if ((t & 63) == 0) red[e][t >> 6] = s;
    }
    __syncthreads();
    if (t < E_) {
        float tot = 0.f;
        #pragma unroll
        for (int w = 0; w < 16; ++w) tot += red[t][w];
        out[t] = tot / ((float)B_ * (float)C_);
    }
}

extern "C" void kernel_launch(void* const* d_in, const int* in_sizes, int n_in,
                              void* d_out, int out_size, void* d_ws, size_t ws_size,
                              hipStream_t stream) {
    const float* logits = (const float*)d_in[0];
    const int*   target = (const int*)d_in[1];
    float* out  = (float*)d_out;
    float* part = (float*)d_ws;
    float* cnts = (float*)((char*)d_ws + COUNTS_OFF);
    float* cabs = (float*)((char*)d_ws + COLABS_OFF);

    hipLaunchKernelGGL(colsum_hist, dim3(NBLK_ + 1), dim3(256), 0, stream,
                       logits, target, part, cnts);
    hipLaunchKernelGGL(colreduce, dim3(CQ_), dim3(256), 0, stream,
                       part, cnts, cabs);
    hipLaunchKernelGGL(final_out, dim3(1), dim3(1024), 0, stream,
                       cabs, out);
}

// Round 14
// 29.118 us; speedup vs baseline: 7.3847x; 1.2224x over previous
//
#include <hip/hip_runtime.h>

// logits: [E=4, B=8192, C=1000] f32 (131 MB, memory-bound), target: [B] i32,
// out: [E] f32.  loss[e] = (1/(B*C)) * sum_c |colsum(logits[e])[c] - hist(target)[c]|
//
// Measured structure decisions:
//  - coop grid.sync: ~100us/sync (R6) -> never.
//  - ticket/fence single-dispatch handoff: nondeterministic (R8 tripwire) -> never.
//  - EACH extra dispatch costs ~4-6us (R11: 3-dispatch lost to 2-dispatch) -> 2 only.
//  - hist in colsum block 0 serializes (R10) -> dedicated extra block (R11-proven).
//  - R12 NaN bug: divergent __syncthreads (wave 7 spanned h==1/h==2 paths, each
//    with its own barrier -> double-signal -> LDS race). Fix: ONE block-uniform
//    barrier outside all h-conditionals.
constexpr int E_  = 4;
constexpr int B_  = 8192;
constexpr int C_  = 1000;
constexpr int CQ_ = C_ / 4;             // 250 float4 column-quads
constexpr int NB_ = 128;                // batch rows per colsum block
constexpr int HALF_ = NB_ / 2;          // 64 rows per half-crew
constexpr int NBLK_   = E_ * B_ / NB_;  // 256 colsum blocks (1/CU, 8 waves/CU)
constexpr int RPE_    = B_ / NB_;       // 64 partial rows per exit
constexpr int RG_     = 4;              // row-groups in finalize
constexpr int RPG_    = RPE_ / RG_;     // 16 rows per row-group

// ws: partial[NBLK_][C_] f32 | counts[C_] f32
constexpr size_t PARTIAL_BYTES = (size_t)NBLK_ * C_ * sizeof(float); // 1,024,000
constexpr size_t COUNTS_OFF    = PARTIAL_BYTES;

// ---- dispatch 1 (257 blocks x 512): 256 colsum blocks + 1 hist block -------
// Colsum block: threads (q = t%250, h = t/250), h in {0,1} active, h==2 idle
// (t=500..511). Each half-crew sums 64 rows of its column-quad (coalesced
// float4); ONE uniform barrier; h==0 combines and stores the partial row.
__global__ __launch_bounds__(512) void colsum_hist(
        const float* __restrict__ logits, const int* __restrict__ target,
        float* __restrict__ partial, float* __restrict__ counts) {
    const int b = blockIdx.x, t = threadIdx.x;

    if (b < NBLK_) {
        __shared__ float4 comb[CQ_];
        const int q = t % CQ_;
        const int h = t / CQ_;
        float4 acc = make_float4(0.f, 0.f, 0.f, 0.f);
        if (h < 2) {
            const float4* base = reinterpret_cast<const float4*>(logits)
                               + (size_t)(b * NB_ + h * HALF_) * CQ_ + q;
            #pragma unroll 8
            for (int r = 0; r < HALF_; ++r) {
                float4 v = base[(size_t)r * CQ_];
                acc.x += v.x; acc.y += v.y; acc.z += v.z; acc.w += v.w;
            }
        }
        if (h == 1) comb[q] = acc;      // no barrier inside divergent region
        __syncthreads();                 // single uniform barrier
        if (h == 0) {
            float4 o = comb[q];
            acc.x += o.x; acc.y += o.y; acc.z += o.z; acc.w += o.w;
            reinterpret_cast<float4*>(partial)[(size_t)b * CQ_ + q] = acc;
        }
    } else {  // b == NBLK_: histogram block (uniform barriers within this block)
        __shared__ int lh[C_];
        for (int i = t; i < C_; i += 512) lh[i] = 0;
        __syncthreads();
        for (int i = t; i < B_; i += 512) atomicAdd(&lh[target[i]], 1);
        __syncthreads();
        for (int i = t; i < C_; i += 512) counts[i] = (float)lh[i];
    }
}

// ---- dispatch 2 (4 blocks x 1024): reduce 64 rows/exit (256 KB) -> out[e] --
__global__ __launch_bounds__(1024) void finalize_partial(
        const float* __restrict__ partial, const float* __restrict__ counts,
        float* __restrict__ out) {
    const int e = blockIdx.x, t = threadIdx.x;
    const int q  = t % CQ_;
    const int rg = t / CQ_;

    __shared__ float4 l2[RG_][CQ_];
    if (t < RG_ * CQ_) {
        const float4* p = reinterpret_cast<const float4*>(partial)
                        + (size_t)(e * RPE_ + rg * RPG_) * CQ_ + q;
        float4 a = make_float4(0.f, 0.f, 0.f, 0.f);
        #pragma unroll 8
        for (int k = 0; k < RPG_; ++k) {
            float4 v = p[(size_t)k * CQ_];
            a.x += v.x; a.y += v.y; a.z += v.z; a.w += v.w;
        }
        l2[rg][q] = a;
    }
    __syncthreads();

    float s = 0.f;
    if (t < CQ_) {
        float4 a = l2[0][t], b2 = l2[1][t], c = l2[2][t], d = l2[3][t];
        float4 cn = reinterpret_cast<const float4*>(counts)[t];
        s = fabsf(a.x + b2.x + c.x + d.x - cn.x)
          + fabsf(a.y + b2.y + c.y + d.y - cn.y)
          + fabsf(a.z + b2.z + c.z + d.z - cn.z)
          + fabsf(a.w + b2.w + c.w + d.w - cn.w);
    }
    #pragma unroll
    for (int off = 32; off > 0; off >>= 1) s += __shfl_down(s, off);
    __shared__ float red[16];
    if ((t & 63) == 0) red[t >> 6] = s;
    __syncthreads();
    if (t == 0) {
        float tot = 0.f;
        #pragma unroll
        for (int w = 0; w < 16; ++w) tot += red[w];
        out[e] = tot / ((float)B_ * (float)C_);
    }
}

extern "C" void kernel_launch(void* const* d_in, const int* in_sizes, int n_in,
                              void* d_out, int out_size, void* d_ws, size_t ws_size,
                              hipStream_t stream) {
    const float* logits = (const float*)d_in[0];
    const int*   target = (const int*)d_in[1];
    float* out  = (float*)d_out;
    float* part = (float*)d_ws;
    float* cnts = (float*)((char*)d_ws + COUNTS_OFF);

    hipLaunchKernelGGL(colsum_hist, dim3(NBLK_ + 1), dim3(512), 0, stream,
                       logits, target, part, cnts);
    hipLaunchKernelGGL(finalize_partial, dim3(E_), dim3(1024), 0, stream,
                       part, cnts, out);
}

// Round 15
// 28.512 us; speedup vs baseline: 7.5417x; 1.0213x over previous
//
#include <hip/hip_runtime.h>

// logits: [E=4, B=8192, C=1000] f32 (131 MB, memory-bound), target: [B] i32,
// out: [E] f32.  loss[e] = (1/(B*C)) * sum_c |colsum(logits[e])[c] - hist(target)[c]|
//
// Measured structure decisions:
//  - coop grid.sync: ~100us/sync (R6) -> never.
//  - ticket/fence single-dispatch handoff: nondeterministic (R8 tripwire) -> never.
//  - EACH extra dispatch costs ~4-6us (R11) -> exactly 2 dispatches.
//  - hist in colsum block 0 serializes (R10) -> dedicated extra block (R11/R14-proven).
//  - partial rows cost tail time (R7 vs R14) -> keep 256 rows (1 MB).
//  - barriers must be block-uniform (R12 NaN) -> single __syncthreads outside
//    all crew conditionals.
//  - R14 = 29.1us with 8 waves/CU colsum; stream floor ~13-14us (R6: L3 serves
//    ~half on replay) -> colsum is latency-bound -> 16 waves/CU via 1024-thr
//    blocks, 4 crews x 32 rows, LDS-combine.
constexpr int E_  = 4;
constexpr int B_  = 8192;
constexpr int C_  = 1000;
constexpr int CQ_ = C_ / 4;             // 250 float4 column-quads
constexpr int NB_ = 128;                // batch rows per colsum block
constexpr int CREWS_ = 4;               // 250-lane crews per block
constexpr int RPC_   = NB_ / CREWS_;    // 32 rows per crew
constexpr int NBLK_  = E_ * B_ / NB_;   // 256 colsum blocks (1/CU, 16 waves/CU)
constexpr int RPE_   = B_ / NB_;        // 64 partial rows per exit
constexpr int RG_    = 4;               // row-groups in finalize
constexpr int RPG_   = RPE_ / RG_;      // 16 rows per row-group

// ws: partial[NBLK_][C_] f32 | counts[C_] f32
constexpr size_t PARTIAL_BYTES = (size_t)NBLK_ * C_ * sizeof(float); // 1,024,000
constexpr size_t COUNTS_OFF    = PARTIAL_BYTES;

// ---- dispatch 1 (257 blocks x 1024): 256 colsum blocks + 1 hist block ------
// Colsum block: q = t%250, h = t/250 in {0..3} active, t>=1000 idle. Crew h
// sums rows [b*128 + h*32, +32) of its column-quad (coalesced float4). Crews
// 1-3 stage to LDS; ONE uniform barrier; crew 0 combines + stores partial row.
__global__ __launch_bounds__(1024) void colsum_hist(
        const float* __restrict__ logits, const int* __restrict__ target,
        float* __restrict__ partial, float* __restrict__ counts) {
    const int b = blockIdx.x, t = threadIdx.x;

    if (b < NBLK_) {
        __shared__ float4 comb[CREWS_ - 1][CQ_];
        const int q = t % CQ_;
        const int h = t / CQ_;
        float4 acc = make_float4(0.f, 0.f, 0.f, 0.f);
        if (h < CREWS_) {
            const float4* base = reinterpret_cast<const float4*>(logits)
                               + (size_t)(b * NB_ + h * RPC_) * CQ_ + q;
            #pragma unroll 8
            for (int r = 0; r < RPC_; ++r) {
                float4 v = base[(size_t)r * CQ_];
                acc.x += v.x; acc.y += v.y; acc.z += v.z; acc.w += v.w;
            }
        }
        if (h >= 1 && h < CREWS_) comb[h - 1][q] = acc;
        __syncthreads();                 // single block-uniform barrier
        if (h == 0) {
            #pragma unroll
            for (int j = 0; j < CREWS_ - 1; ++j) {
                float4 o = comb[j][q];
                acc.x += o.x; acc.y += o.y; acc.z += o.z; acc.w += o.w;
            }
            reinterpret_cast<float4*>(partial)[(size_t)b * CQ_ + q] = acc;
        }
    } else {  // b == NBLK_: histogram block (own uniform barriers)
        __shared__ int lh[C_];
        for (int i = t; i < C_; i += 1024) lh[i] = 0;
        __syncthreads();
        for (int i = t; i < B_; i += 1024) atomicAdd(&lh[target[i]], 1);
        __syncthreads();
        for (int i = t; i < C_; i += 1024) counts[i] = (float)lh[i];
    }
}

// ---- dispatch 2 (4 blocks x 1024): reduce 64 rows/exit (256 KB) -> out[e] --
__global__ __launch_bounds__(1024) void finalize_partial(
        const float* __restrict__ partial, const float* __restrict__ counts,
        float* __restrict__ out) {
    const int e = blockIdx.x, t = threadIdx.x;
    const int q  = t % CQ_;
    const int rg = t / CQ_;

    __shared__ float4 l2[RG_][CQ_];
    if (t < RG_ * CQ_) {
        const float4* p = reinterpret_cast<const float4*>(partial)
                        + (size_t)(e * RPE_ + rg * RPG_) * CQ_ + q;
        float4 a = make_float4(0.f, 0.f, 0.f, 0.f);
        #pragma unroll 8
        for (int k = 0; k < RPG_; ++k) {
            float4 v = p[(size_t)k * CQ_];
            a.x += v.x; a.y += v.y; a.z += v.z; a.w += v.w;
        }
        l2[rg][q] = a;
    }
    __syncthreads();

    float s = 0.f;
    if (t < CQ_) {
        float4 a = l2[0][t], b2 = l2[1][t], c = l2[2][t], d = l2[3][t];
        float4 cn = reinterpret_cast<const float4*>(counts)[t];
        s = fabsf(a.x + b2.x + c.x + d.x - cn.x)
          + fabsf(a.y + b2.y + c.y + d.y - cn.y)
          + fabsf(a.z + b2.z + c.z + d.z - cn.z)
          + fabsf(a.w + b2.w + c.w + d.w - cn.w);
    }
    #pragma unroll
    for (int off = 32; off > 0; off >>= 1) s += __shfl_down(s, off);
    __shared__ float red[16];
    if ((t & 63) == 0) red[t >> 6] = s;
    __syncthreads();
    if (t == 0) {
        float tot = 0.f;
        #pragma unroll
        for (int w = 0; w < 16; ++w) tot += red[w];
        out[e] = tot / ((float)B_ * (float)C_);
    }
}

extern "C" void kernel_launch(void* const* d_in, const int* in_sizes, int n_in,
                              void* d_out, int out_size, void* d_ws, size_t ws_size,
                              hipStream_t stream) {
    const float* logits = (const float*)d_in[0];
    const int*   target = (const int*)d_in[1];
    float* out  = (float*)d_out;
    float* part = (float*)d_ws;
    float* cnts = (float*)((char*)d_ws + COUNTS_OFF);

    hipLaunchKernelGGL(colsum_hist, dim3(NBLK_ + 1), dim3(1024), 0, stream,
                       logits, target, part, cnts);
    hipLaunchKernelGGL(finalize_partial, dim3(E_), dim3(1024), 0, stream,
                       part, cnts, out);
}